// Round 11
// baseline (107.910 us; speedup 1.0000x reference)
//
#include <hip/hip_runtime.h>

// RankPool1d: window=16, stride=1, pad=8 (zeros), rank=8 (0-based 7),
// stable argsort tie-break. Outputs: values f32 [OUT_LEN], sel (as f32) [OUT_LEN].
//
// R11: mask-register-free hot path (theory: cmp->vcc/carry->addc/cndmask
// round-trips are the 50% stall at 3 waves/SIMD).
//   (a<b)  = __float_as_uint(a-b)>>31          (v_sub + v_lshr, pure VGPR)
//   R[j] += c1+c2                              (v_add3)
//   match  = ((R[j]^t)-1)>>31 (arith) -> -1/0  (v_xor + v_add + v_ashr)
//   val/sel accumulate via (msk&x)|(~msk&acc)  (v_bfi_b32 chains)
// Exactness: inputs are finite N(0,1) floats + zero padding; a-b is never
// subnormal-nonzero for distinct inputs at this scale, a==b -> +0 -> bit 0.
//
// Diag clone (x3 reps, memory-clobber separated) runs second so true
// VALUBusy/VGPR land in rocprof top-5. Outputs idempotent. Bench dur ~4x real.
//
// LAUNCH BOUNDS: bare (256) ONLY (second arg -> scratch spill, R4/R5).

constexpr int L_IN    = 4194304;
constexpr int OUT_LEN = L_IN + 1;      // 4194305
constexpr int MOUT    = 16;
constexpr int TPB     = 256;
constexpr int NTH     = (OUT_LEN - 1) / MOUT;   // 262144
constexpr int NBLK    = NTH / TPB;              // 1024

__device__ __forceinline__ unsigned lt01(float a, float b) {
    return __float_as_uint(a - b) >> 31;        // (a<b) as 0/1, no mask regs
}

__device__ __forceinline__ void rankpool_body(const float* __restrict__ x,
                                              float* __restrict__ dout) {
    const int t    = blockIdx.x * TPB + threadIdx.x;   // 0..262143
    const int lane = threadIdx.x & 63;
    const int o0   = t * MOUT;
    const int base = o0 - 8;
    const bool isLast = (t == NTH - 1);

    // ---- load 32 inputs (windows m=0..15 need base..base+30; extra +31) ----
    float w[32];
    if (base >= 0 && base + 32 <= L_IN) {
        const float4* p = reinterpret_cast<const float4*>(x + base);  // 16B aligned
        #pragma unroll
        for (int q = 0; q < 8; ++q) {
            float4 v = p[q];
            w[4*q+0] = v.x; w[4*q+1] = v.y; w[4*q+2] = v.z; w[4*q+3] = v.w;
        }
    } else {
        #pragma unroll
        for (int i = 0; i < 32; ++i) {
            int g = base + i;
            w[i] = (g >= 0 && g < L_IN) ? x[g] : 0.0f;   // PAD_VALUE = 0
        }
    }

    // ---- biased ranks for window 0 (R[j] = stable rank; init R[j]=j) ----
    int R[32];
    #pragma unroll
    for (int j = 0; j < 16; ++j) R[j] = j;
    #pragma unroll
    for (int j = 0; j < 16; ++j) {
        #pragma unroll
        for (int k = j + 1; k < 16; ++k) {
            unsigned c = lt01(w[k], w[j]);   // w[k] < w[j]
            R[j] += c;
            R[k] -= c;
        }
    }

    // ---- 16 windows: bfi-select rank==7 (biased 7+m), f4 stores, slide ----
    unsigned pk[4] = {0u, 0u, 0u, 0u};   // 16 sel bytes
    float va[4];                          // 4-value store ring
    #pragma unroll
    for (int m = 0; m < MOUT; ++m) {
        const int t7 = 7 + m;
        unsigned vb = 0u;                 // value bits accumulator
        int sel = 0;
        #pragma unroll
        for (int j = m; j < m + 16; ++j) {
            int e   = R[j] ^ t7;                    // 0 iff match
            int msk = (e - 1) >> 31;                // -1 iff match (arith shr)
            vb  = ((unsigned)msk & __float_as_uint(w[j])) | (~(unsigned)msk & vb);
            sel = (msk & (j - m)) | (~msk & sel);
        }
        va[m & 3] = __uint_as_float(vb);
        pk[m >> 2] |= ((unsigned)sel) << (8 * (m & 3));
        if ((m & 3) == 3)   // o0 + m-3 is a multiple of 4 -> aligned
            *reinterpret_cast<float4*>(dout + o0 + (m - 3)) =
                make_float4(va[0], va[1], va[2], va[3]);

        if (m < MOUT - 1) {
            const float wm = w[m];            // departing (oldest)
            const float wn = w[m + 16];       // entering (newest)
            unsigned s = 0;
            #pragma unroll
            for (int j = m + 1; j < m + 16; ++j) {
                unsigned c1 = lt01(w[j], wm);
                unsigned c2 = lt01(wn, w[j]);
                R[j] += (int)(c1 + c2);       // v_add3
                s    += c2;
            }
            R[m + 16] = 16 + m - (int)s;      // (15-s) + (m+1) bias
        }
    }

    // ---- sel stores: aligned float4 groups ----
    unsigned pn = __shfl_down(pk[0], 1, 64);  // lane+1's first 4 sel bytes
    float* s0 = dout + OUT_LEN + o0;          // (OUT_LEN+o0+3) % 4 == 0
    #pragma unroll
    for (int g = 0; g < 3; ++g) {
        unsigned a = pk[g], b = pk[g + 1];
        *reinterpret_cast<float4*>(s0 + 3 + 4 * g) =
            make_float4((float)( a >> 24),
                        (float)( b        & 0xffu),
                        (float)((b >>  8) & 0xffu),
                        (float)((b >> 16) & 0xffu));
    }
    if (lane < 63) {
        *reinterpret_cast<float4*>(s0 + 15) =
            make_float4((float)( pk[3] >> 24),
                        (float)( pn        & 0xffu),
                        (float)((pn >>  8) & 0xffu),
                        (float)((pn >> 16) & 0xffu));
    } else {
        s0[15] = (float)(pk[3] >> 24);        // own last byte only
    }
    if (lane == 0) {
        s0[0] = (float)( pk[0]        & 0xffu);
        s0[1] = (float)((pk[0] >>  8) & 0xffu);
        s0[2] = (float)((pk[0] >> 16) & 0xffu);
    }

    // ---- final output OUT_LEN-1 (window m=16 of last thread: w[16..31]) ----
    if (isLast) {
        const float wm = w[15], wn = w[31];
        unsigned s = 0;
        #pragma unroll
        for (int j = 16; j < 31; ++j) {
            unsigned c1 = lt01(w[j], wm);
            unsigned c2 = lt01(wn, w[j]);
            R[j] += (int)(c1 + c2);
            s    += c2;
        }
        R[31] = 31 - (int)s;                  // (15-s) + 16 bias
        unsigned vb = 0u; int sel = 0;
        #pragma unroll
        for (int j = 16; j < 32; ++j) {
            int e   = R[j] ^ 23;              // 7 + 16
            int msk = (e - 1) >> 31;
            vb  = ((unsigned)msk & __float_as_uint(w[j])) | (~(unsigned)msk & vb);
            sel = (msk & (j - 16)) | (~msk & sel);
        }
        dout[OUT_LEN - 1]     = __uint_as_float(vb);
        dout[2 * OUT_LEN - 1] = (float)sel;
    }
}

__global__ __launch_bounds__(TPB) void rankpool_kernel(const float* __restrict__ x,
                                                       float* __restrict__ dout) {
    rankpool_body(x, dout);
}

// x3 idempotent reps; memory clobber keeps each rep's loads/stores real.
// Lands >43us -> visible in rocprof top-5 with true counters.
__global__ __launch_bounds__(TPB) void rankpool_diag(const float* __restrict__ x,
                                                     float* __restrict__ dout) {
    for (int rep = 0; rep < 3; ++rep) {
        rankpool_body(x, dout);
        asm volatile("" ::: "memory");
    }
}

extern "C" void kernel_launch(void* const* d_in, const int* in_sizes, int n_in,
                              void* d_out, int out_size, void* d_ws, size_t ws_size,
                              hipStream_t stream) {
    const float* x = (const float*)d_in[0];
    float* out = (float*)d_out;
    rankpool_kernel<<<NBLK, TPB, 0, stream>>>(x, out);
    rankpool_diag<<<NBLK, TPB, 0, stream>>>(x, out);
}